// Round 2
// baseline (423.711 us; speedup 1.0000x reference)
//
#include <hip/hip_runtime.h>

// Frame-wise E^H D E exact NDFT via separable phasors as two complex GEMMs on
// fp16 matrix cores (fp32 accumulate).
// v3: fragment-ordered LDS (zero bank conflicts, contiguous 1KB wave accesses),
// barrier-phased prefetch (loads issued right after __syncthreads, consumed at
// top of next iter; sched_barrier(0) pins them ahead of MFMA), 256-thread
// blocks at 4 blocks/CU so barrier drains are covered by other blocks.

#define NT 16
#define NK 2048
#define NXY 128
#define NC 8

typedef _Float16 f16x8 __attribute__((ext_vector_type(8)));
typedef float f32x4 __attribute__((ext_vector_type(4)));

union F8 { f16x8 h; uint u[4]; };

#define MFMA16(a, b, c) __builtin_amdgcn_mfma_f32_16x16x32_f16((a), (b), (c), 0, 0, 0)

__device__ __forceinline__ uint pack2h(float a, float b) {
    union { _Float16 h[2]; uint u; } p;
    p.h[0] = (_Float16)a; p.h[1] = (_Float16)b;
    return p.u;
}
__device__ __forceinline__ float2 unpack2h(uint v) {
    union { uint u; _Float16 h[2]; } p;
    p.u = v;
    return make_float2((float)p.h[0], (float)p.h[1]);
}
__device__ __forceinline__ uint rot16(uint v) { return (v >> 16) | (v << 16); }

// ---------------------------------------------------------------------------
// ktrajT[d][t][k] = ktraj[d][k][t]
// ---------------------------------------------------------------------------
__global__ __launch_bounds__(256) void prep_ktraj(const float* __restrict__ ktraj,
                                                  float* __restrict__ ktrajT) {
    const int idx = blockIdx.x * 256 + threadIdx.x;          // < 2*NK*NT = 65536
    const int t = idx & 15, k = (idx >> 4) & (NK - 1), d = idx >> 15;
    ktrajT[((size_t)d * NT + t) * NK + k] = ktraj[((size_t)d * NK + k) * NT + t];
}

// ---------------------------------------------------------------------------
// ExC[t][kt][xc][kp][xq], EyC[t][kt][yc][kp][yq]; value exp(-i*k*(x-64)).
// ---------------------------------------------------------------------------
__global__ __launch_bounds__(256) void prep_phasA(const float* __restrict__ ktrajT,
                                                  uint* __restrict__ ExC,
                                                  uint* __restrict__ EyC) {
    const int t = blockIdx.x;
    const int k = blockIdx.y * 2 + (threadIdx.x >> 7);
    const int x = threadIdx.x & 127;
    const float kx = ktrajT[(size_t)t * NK + k];
    const float ky = ktrajT[(size_t)(NT + t) * NK + k];
    const float xm = (float)(x - 64);
    const size_t off = ((size_t)(t * 16 + (k >> 7)) * 8 + (x >> 4)) * 2048 +
                       (size_t)(k & 127) * 16 + (x & 15);
    float s, c;
    __sincosf(-kx * xm, &s, &c);
    ExC[off] = pack2h(c, s);
    __sincosf(-ky * xm, &s, &c);
    EyC[off] = pack2h(c, s);
}

// ---------------------------------------------------------------------------
// ExT[t][kc][x][kq]
// ---------------------------------------------------------------------------
__global__ __launch_bounds__(256) void prep_phasB(const float* __restrict__ ktrajT,
                                                  uint* __restrict__ ExT) {
    const int t = blockIdx.x, x = blockIdx.y;
    const int k = blockIdx.z * 256 + threadIdx.x;
    const float kx = ktrajT[(size_t)t * NK + k];
    float s, c;
    __sincosf(-kx * (float)(x - 64), &s, &c);
    ExT[((size_t)(t * 64 + (k >> 5)) * 128 + x) * 32 + (k & 31)] = pack2h(c, s);
}

// ---------------------------------------------------------------------------
// srcB in MFMA-fragment order: [t][c][ch8][mf8][r16][q4][xq4] dwords,
// element = (smap[c,x,y] * img[x,y,t]) with x = ch*16 + q*4 + xq, y = mf*16 + r.
// Each 2048-dword block = one chunk A-tile, linear in fragment order.
// ---------------------------------------------------------------------------
__global__ __launch_bounds__(256) void prep_src(const float* __restrict__ xin,
                                                const float* __restrict__ csmap,
                                                uint* __restrict__ srcB) {
    const int idx = blockIdx.x * 256 + threadIdx.x;   // < 16*8*16384
    const int tc = idx >> 14, t = tc >> 3, c = tc & 7;
    const int rest = idx & 16383;
    const int ch = rest >> 11, mf = (rest >> 8) & 7, r = (rest >> 4) & 15, xl = rest & 15;
    const int x = ch * 16 + xl, y = mf * 16 + r;
    const float ir = xin[(size_t)(x * NXY + y) * NT + t];
    const float ii = xin[(size_t)NXY * NXY * NT + (size_t)(x * NXY + y) * NT + t];
    const float sr = csmap[(size_t)c * 2 * NXY * NXY + x * NXY + y];
    const float si = csmap[(size_t)c * 2 * NXY * NXY + NXY * NXY + x * NXY + y];
    srcB[idx] = pack2h(sr * ir - si * ii, sr * ii + si * ir);
}

// ---------------------------------------------------------------------------
// fwd_gemm: block = (t, c, kt of 64 kpoints), 256 thr (4 waves: 2 mh x 2 nq).
// C1[y=128, kp=64] over K'=256 (x r/i-interleaved), 8 chunks of 16 x-dwords.
// A staged linearly in fragment order (contiguous loads+stores+reads).
// Epilogue: y-reduce with Ey via LDS partial combine across mh halves.
// ---------------------------------------------------------------------------
__global__ __launch_bounds__(256, 4) void fwd_gemm(const uint* __restrict__ ExC,
                                                   const uint* __restrict__ EyC,
                                                   const uint* __restrict__ srcB,
                                                   const float* __restrict__ dcomp,
                                                   float2* __restrict__ g) {
    const int t = blockIdx.x, c = blockIdx.y, kt = blockIdx.z;
    const int tid = threadIdx.x, lane = tid & 63, ws = tid >> 6;
    const int quad = lane >> 4, l15 = lane & 15;
    const int mh = ws >> 1, nq = ws & 1;

    __shared__ __align__(16) _Float16 As[2][4096];

    f32x4 accr[4][2], acci[4][2];
#pragma unroll
    for (int mf = 0; mf < 4; ++mf)
#pragma unroll
        for (int nf = 0; nf < 2; ++nf) { accr[mf][nf] = (f32x4)0.0f; acci[mf][nf] = (f32x4)0.0f; }

    const uint* srcT = srcB + (size_t)(t * NC + c) * 16384;
    const uint* exB = ExC + (size_t)(t * 16 + (kt >> 1)) * 16384;
    const int kin0 = (kt & 1) * 64 + nq * 32;            // kp base within 128-tile

    // prologue: stage + B loads for chunk 0
    F8 vA0 = *(const F8*)(srcT + tid * 8);
    F8 vA1 = *(const F8*)(srcT + tid * 8 + 4);
    F8 Bc0 = *(const F8*)(exB + (kin0 + l15) * 16 + quad * 4);
    F8 Bc1 = *(const F8*)(exB + (kin0 + 16 + l15) * 16 + quad * 4);

#pragma unroll 2
    for (int ch = 0; ch < 8; ++ch) {
        const int buf = ch & 1;
        *(F8*)&As[buf][tid * 16] = vA0;
        *(F8*)&As[buf][tid * 16 + 8] = vA1;
        __syncthreads();
        // prefetch next chunk (consumed at top of next iter / next MFMA phase)
        const int chn = ch < 7 ? ch + 1 : 7;
        vA0 = *(const F8*)(srcT + chn * 2048 + tid * 8);
        vA1 = *(const F8*)(srcT + chn * 2048 + tid * 8 + 4);
        F8 Bn0 = *(const F8*)(exB + chn * 2048 + (kin0 + l15) * 16 + quad * 4);
        F8 Bn1 = *(const F8*)(exB + chn * 2048 + (kin0 + 16 + l15) * 16 + quad * 4);
        __builtin_amdgcn_sched_barrier(0);
#pragma unroll
        for (int mf = 0; mf < 4; ++mf) {
            F8 Ap = *(const F8*)&As[buf][(mh * 4 + mf) * 512 + l15 * 32 + quad * 8];
            F8 Ar, Ai;
#pragma unroll
            for (int d = 0; d < 4; ++d) {
                Ar.u[d] = Ap.u[d] ^ 0x80000000u;   // (sR, -sI)
                Ai.u[d] = rot16(Ap.u[d]);          // (sI,  sR)
            }
            accr[mf][0] = MFMA16(Ar.h, Bc0.h, accr[mf][0]);
            acci[mf][0] = MFMA16(Ai.h, Bc0.h, acci[mf][0]);
            accr[mf][1] = MFMA16(Ar.h, Bc1.h, accr[mf][1]);
            acci[mf][1] = MFMA16(Ai.h, Bc1.h, acci[mf][1]);
        }
        Bc0 = Bn0; Bc1 = Bn1;
    }

    // epilogue: partial y-reduction with Ey per mh-half, LDS combine
    __syncthreads();
    float* red = (float*)(&As[0][0]);          // 2*64*2 floats, As no longer needed
    const uint* eyB = EyC + (size_t)(t * 16 + (kt >> 1)) * 16384;
#pragma unroll
    for (int nf = 0; nf < 2; ++nf) {
        const int kin = kin0 + nf * 16 + l15;
        float kdr = 0.f, kdi = 0.f;
#pragma unroll
        for (int mf = 0; mf < 4; ++mf) {
            const int yc = mh * 4 + mf;
            F8 e4 = *(const F8*)(eyB + yc * 2048 + kin * 16 + quad * 4);
#pragma unroll
            for (int rr = 0; rr < 4; ++rr) {
                float2 ey = unpack2h(e4.u[rr]);
                float cr = accr[mf][nf][rr], ci = acci[mf][nf][rr];
                kdr += ey.x * cr - ey.y * ci;
                kdi += ey.x * ci + ey.y * cr;
            }
        }
        kdr += __shfl_xor(kdr, 16); kdr += __shfl_xor(kdr, 32);
        kdi += __shfl_xor(kdi, 16); kdi += __shfl_xor(kdi, 32);
        if (lane < 16) {
            const int kl = nq * 32 + nf * 16 + l15;       // 0..63
            red[(mh * 64 + kl) * 2] = kdr;
            red[(mh * 64 + kl) * 2 + 1] = kdi;
        }
    }
    __syncthreads();
    if (tid < 64) {
        const int kpoint = kt * 64 + tid;
        const float kdr = red[tid * 2] + red[(64 + tid) * 2];
        const float kdi = red[tid * 2 + 1] + red[(64 + tid) * 2 + 1];
        const float w = dcomp[(size_t)kpoint * NT + t] * (1.0f / 16384.0f);
        g[(size_t)(t * NC + c) * NK + kpoint] = make_float2(kdr * w, kdi * w);
    }
}

// ---------------------------------------------------------------------------
// adj_gemm helpers
// ---------------------------------------------------------------------------
struct BuildRegs { float4 ga, gb; uint ev0, ev1, ev2, ev3; };

__device__ __forceinline__ void build_load(BuildRegs& b, const float2* __restrict__ gRow,
                                           const uint* __restrict__ eyT, int ybank, int kp) {
    b.ga = *(const float4*)(gRow + kp);
    b.gb = *(const float4*)(gRow + kp + 2);
    const uint* ey = eyT + (size_t)(kp >> 7) * 16384 + (size_t)(kp & 127) * 16 + ybank;
    b.ev0 = ey[0]; b.ev1 = ey[16]; b.ev2 = ey[32]; b.ev3 = ey[48];
}
__device__ __forceinline__ F8 build_pack(const BuildRegs& b) {
    F8 w; float2 e;
    e = unpack2h(b.ev0); w.u[0] = pack2h(e.x*b.ga.x + e.y*b.ga.y, e.x*b.ga.y - e.y*b.ga.x);
    e = unpack2h(b.ev1); w.u[1] = pack2h(e.x*b.ga.z + e.y*b.ga.w, e.x*b.ga.w - e.y*b.ga.z);
    e = unpack2h(b.ev2); w.u[2] = pack2h(e.x*b.gb.x + e.y*b.gb.y, e.x*b.gb.y - e.y*b.gb.x);
    e = unpack2h(b.ev3); w.u[3] = pack2h(e.x*b.gb.z + e.y*b.gb.w, e.x*b.gb.w - e.y*b.gb.z);
    return w;
}

// ---------------------------------------------------------------------------
// adj_gemm: block = (t, ytile of 8 y, kz of 4 k-segments), 256 thr (4 waves).
// C3[m=(yloc*8+c)=64, x=128] over K'=1024/block, 16 chunks of 32 kpoints.
// Ts in fragment order: frag fb = mf*2+ks, 1KB each; build writes contiguous,
// MFMA reads contiguous. Builds+B prefetched one chunk ahead (post-barrier
// issue, pre-barrier consume). Epilogue: conj(smap) combine + atomicAdd.
// ---------------------------------------------------------------------------
__global__ __launch_bounds__(256, 4) void adj_gemm(const uint* __restrict__ ExT,
                                                   const uint* __restrict__ EyC,
                                                   const float2* __restrict__ g,
                                                   const float* __restrict__ csmap,
                                                   float* __restrict__ out) {
    const int t = blockIdx.x, yt = blockIdx.y, kz = blockIdx.z, ybase = yt * 8;
    const int tid = threadIdx.x, lane = tid & 63, nq = tid >> 6;
    const int quad = lane >> 4, l15 = lane & 15;

    __shared__ __align__(16) _Float16 Ts[2][4096];

    f32x4 accr[4][2], acci[4][2];
#pragma unroll
    for (int mf = 0; mf < 4; ++mf)
#pragma unroll
        for (int nf = 0; nf < 2; ++nf) { accr[mf][nf] = (f32x4)0.0f; acci[mf][nf] = (f32x4)0.0f; }

    // build mapping: row bm (0..63), kp quad bu (0..3), two ks per thread
    const int bm = tid >> 2, bu = tid & 3;
    const int bc = bm & 7, by = ybase + (bm >> 3);
    const float2* gRow = g + (size_t)(t * NC + bc) * NK;
    const uint* eyT = EyC + (size_t)t * 262144;
    const int ybank = (by >> 4) * 2048 + (by & 15);
    const int tsoff = (bm & 15) * 32 + bu * 8;
    const int fb0 = (bm >> 4) * 2;

    const uint* exT0 = ExT + (size_t)(t * 64 + kz * 16) * 4096;
    const int xcol = (nq * 32 + l15) * 32;               // nf0; nf1 adds 512

    BuildRegs br0, br1;
    build_load(br0, gRow, eyT, ybank, kz * 512 + bu * 4);
    build_load(br1, gRow, eyT, ybank, kz * 512 + 16 + bu * 4);
    F8 Bc00 = *(const F8*)(exT0 + xcol + quad * 4);
    F8 Bc01 = *(const F8*)(exT0 + xcol + 16 + quad * 4);
    F8 Bc10 = *(const F8*)(exT0 + xcol + 512 + quad * 4);
    F8 Bc11 = *(const F8*)(exT0 + xcol + 512 + 16 + quad * 4);

#pragma unroll 2
    for (int ch = 0; ch < 16; ++ch) {
        const int buf = ch & 1;
        // pack + write chunk ch (builds issued one chunk ago, latency hidden)
        *(F8*)&Ts[buf][fb0 * 512 + tsoff] = build_pack(br0);
        *(F8*)&Ts[buf][(fb0 + 1) * 512 + tsoff] = build_pack(br1);
        __syncthreads();
        // prefetch chunk ch+1 (consumed before next barrier -> never drained cold)
        const int chn = ch < 15 ? ch + 1 : 15;
        const int kpb = kz * 512 + chn * 32;
        build_load(br0, gRow, eyT, ybank, kpb + bu * 4);
        build_load(br1, gRow, eyT, ybank, kpb + 16 + bu * 4);
        const uint* exN = exT0 + (size_t)chn * 4096;
        F8 Bn00 = *(const F8*)(exN + xcol + quad * 4);
        F8 Bn01 = *(const F8*)(exN + xcol + 16 + quad * 4);
        F8 Bn10 = *(const F8*)(exN + xcol + 512 + quad * 4);
        F8 Bn11 = *(const F8*)(exN + xcol + 512 + 16 + quad * 4);
        __builtin_amdgcn_sched_barrier(0);
        // MFMA phase: zero global waits, contiguous 1KB LDS reads
#pragma unroll
        for (int mf = 0; mf < 4; ++mf) {
            {
                F8 Ap = *(const F8*)&Ts[buf][(mf * 2) * 512 + l15 * 32 + quad * 8];
                F8 Ai;
#pragma unroll
                for (int d = 0; d < 4; ++d) Ai.u[d] = rot16(Ap.u[d]) ^ 0x80000000u;
                accr[mf][0] = MFMA16(Ap.h, Bc00.h, accr[mf][0]);
                acci[mf][0] = MFMA16(Ai.h, Bc00.h, acci[mf][0]);
                accr[mf][1] = MFMA16(Ap.h, Bc10.h, accr[mf][1]);
                acci[mf][1] = MFMA16(Ai.h, Bc10.h, acci[mf][1]);
            }
            {
                F8 Ap = *(const F8*)&Ts[buf][(mf * 2 + 1) * 512 + l15 * 32 + quad * 8];
                F8 Ai;
#pragma unroll
                for (int d = 0; d < 4; ++d) Ai.u[d] = rot16(Ap.u[d]) ^ 0x80000000u;
                accr[mf][0] = MFMA16(Ap.h, Bc01.h, accr[mf][0]);
                acci[mf][0] = MFMA16(Ai.h, Bc01.h, acci[mf][0]);
                accr[mf][1] = MFMA16(Ap.h, Bc11.h, accr[mf][1]);
                acci[mf][1] = MFMA16(Ai.h, Bc11.h, acci[mf][1]);
            }
        }
        Bc00 = Bn00; Bc01 = Bn01; Bc10 = Bn10; Bc11 = Bn11;
    }

    // epilogue: coil-combine with conj(smap), atomicAdd into zeroed out
#pragma unroll
    for (int mf = 0; mf < 4; ++mf)
#pragma unroll
        for (int nf = 0; nf < 2; ++nf) {
            const int y = ybase + mf * 2 + (quad >> 1);
            const int xx = nq * 32 + nf * 16 + l15;
            float or_ = 0.f, oi_ = 0.f;
#pragma unroll
            for (int rr = 0; rr < 4; ++rr) {
                const int cc = (quad & 1) * 4 + rr;
                const float sr = csmap[(size_t)cc * 2 * NXY * NXY + xx * NXY + y];
                const float si = csmap[(size_t)cc * 2 * NXY * NXY + NXY * NXY + xx * NXY + y];
                const float xr = accr[mf][nf][rr], xi = acci[mf][nf][rr];
                or_ += sr * xr + si * xi;
                oi_ += sr * xi - si * xr;
            }
            or_ += __shfl_xor(or_, 16);
            oi_ += __shfl_xor(oi_, 16);
            if ((lane & 16) == 0) {
                atomicAdd(out + (size_t)(xx * NXY + y) * NT + t, or_);
                atomicAdd(out + (size_t)NXY * NXY * NT + (size_t)(xx * NXY + y) * NT + t, oi_);
            }
        }
}

// ---------------------------------------------------------------------------
extern "C" void kernel_launch(void* const* d_in, const int* in_sizes, int n_in,
                              void* d_out, int out_size, void* d_ws, size_t ws_size,
                              hipStream_t stream) {
    const float* xin   = (const float*)d_in[0];  // (2,128,128,16)
    const float* ktraj = (const float*)d_in[1];  // (2,2048,16)
    const float* csmap = (const float*)d_in[2];  // (8,2,128,128)
    const float* dcomp = (const float*)d_in[3];  // (2048,16)
    float* out = (float*)d_out;                  // (2,128,128,16)

    const size_t TBL = (size_t)NT * NK * NXY;            // 4.19M dwords per table
    uint* ExC  = (uint*)d_ws;                            // [t][kt][xc][kp][xq]
    uint* ExT  = ExC + TBL;                              // [t][kc][x][kq]
    uint* EyC  = ExT + TBL;                              // [t][kt][yc][kp][yq]
    uint* srcB = EyC + TBL;                              // fragment-ordered
    float2* g  = (float2*)(srcB + (size_t)NT * NC * NXY * NXY);  // [t][c][k]
    float* ktrajT = (float*)(g + (size_t)NT * NC * NK);  // [d][t][k]

    hipMemsetAsync(d_out, 0, (size_t)out_size, stream);  // adj accumulates atomically
    prep_ktraj<<<dim3(2 * NK * NT / 256), 256, 0, stream>>>(ktraj, ktrajT);
    prep_phasA<<<dim3(NT, NK / 2), 256, 0, stream>>>(ktrajT, ExC, EyC);
    prep_phasB<<<dim3(NT, NXY, NK / 256), 256, 0, stream>>>(ktrajT, ExT);
    prep_src<<<dim3((NT * NC * NXY * NXY) / 256), 256, 0, stream>>>(xin, csmap, srcB);
    fwd_gemm<<<dim3(NT, NC, 32), 256, 0, stream>>>(ExC, EyC, srcB, dcomp, g);
    adj_gemm<<<dim3(NT, NXY / 8, 4), 256, 0, stream>>>(ExT, EyC, g, csmap, out);
}

// Round 3
// 339.750 us; speedup vs baseline: 1.2471x; 1.2471x over previous
//
#include <hip/hip_runtime.h>

// Frame-wise E^H D E exact NDFT via separable phasors as two complex GEMMs on
// fp16 matrix cores (fp32 accumulate).
// v4 = verified v0 structure (276.5us) + two isolated changes:
//  1) adj_gemm: kz=4 k-range split (grid z=4, atomicAdd epilogue on zeroed out)
//     -> 4 blocks/CU instead of 1, barrier/build-latency overlaps across blocks.
//     Kernel body otherwise byte-identical to v0 (48 VGPR, no spill risk).
//  2) prep_tables (128-block serial recurrence, scattered ExT stores) replaced
//     by direct-sincos kernels writing the SAME layouts with coalesced stores.

#define NT 16
#define NK 2048
#define NXY 128
#define NC 8

typedef _Float16 f16x8 __attribute__((ext_vector_type(8)));
typedef float f32x4 __attribute__((ext_vector_type(4)));

union F8 { f16x8 h; uint u[4]; };

#define MFMA16(a, b, c) __builtin_amdgcn_mfma_f32_16x16x32_f16((a), (b), (c), 0, 0, 0)

__device__ __forceinline__ uint pack2h(float a, float b) {
    union { _Float16 h[2]; uint u; } p;
    p.h[0] = (_Float16)a; p.h[1] = (_Float16)b;
    return p.u;
}
__device__ __forceinline__ float2 unpack2h(uint v) {
    union { uint u; _Float16 h[2]; } p;
    p.u = v;
    return make_float2((float)p.h[0], (float)p.h[1]);
}
__device__ __forceinline__ uint rot16(uint v) { return (v >> 16) | (v << 16); }

// ---------------------------------------------------------------------------
// ExC[t][k][x], EyC[t][k][y]; Ex[k,x] = exp(-i*kx*(x-64)).  Direct sincos,
// lanes = x -> contiguous 512B store runs.  k broadcast per half-block.
// ---------------------------------------------------------------------------
__global__ __launch_bounds__(256) void prep_phasA(const float* __restrict__ ktraj,
                                                  uint* __restrict__ ExC,
                                                  uint* __restrict__ EyC) {
    const int t = blockIdx.x;
    const int k = blockIdx.y * 2 + (threadIdx.x >> 7);
    const int x = threadIdx.x & 127;
    const float kx = ktraj[(size_t)k * NT + t];
    const float ky = ktraj[(size_t)(NK + k) * NT + t];
    const float xm = (float)(x - 64);
    const size_t off = ((size_t)t * NK + k) * NXY + x;
    float s, c;
    __sincosf(-kx * xm, &s, &c);
    ExC[off] = pack2h(c, s);
    __sincosf(-ky * xm, &s, &c);
    EyC[off] = pack2h(c, s);
}

// ---------------------------------------------------------------------------
// ExT[t][x][k]; lanes = k -> contiguous 1KB store runs.
// ---------------------------------------------------------------------------
__global__ __launch_bounds__(256) void prep_phasB(const float* __restrict__ ktraj,
                                                  uint* __restrict__ ExT) {
    const int t = blockIdx.x, x = blockIdx.y;
    const int k = blockIdx.z * 256 + threadIdx.x;
    const float kx = ktraj[(size_t)k * NT + t];
    float s, c;
    __sincosf(-kx * (float)(x - 64), &s, &c);
    ExT[((size_t)t * NXY + x) * NK + k] = pack2h(c, s);
}

// ---------------------------------------------------------------------------
// srcB[t][c][y][x] = (smap[c,x,y] * img[x,y,t]) as packed complex fp16
// ---------------------------------------------------------------------------
__global__ __launch_bounds__(256) void prep_src(const float* __restrict__ xin,
                                                const float* __restrict__ csmap,
                                                uint* __restrict__ srcB) {
    const int idx = blockIdx.x * 256 + threadIdx.x;   // < 16*8*128*128
    const int x = idx & 127, y = (idx >> 7) & 127, c = (idx >> 14) & 7, t = idx >> 17;
    const float ir = xin[(size_t)(x * NXY + y) * NT + t];
    const float ii = xin[(size_t)NXY * NXY * NT + (size_t)(x * NXY + y) * NT + t];
    const float sr = csmap[(size_t)c * 2 * NXY * NXY + x * NXY + y];
    const float si = csmap[(size_t)c * 2 * NXY * NXY + NXY * NXY + x * NXY + y];
    srcB[(size_t)((t * NC + c) * NXY + y) * NXY + x] =
        pack2h(sr * ir - si * ii, sr * ii + si * ir);
}

// ---------------------------------------------------------------------------
// fwd_gemm: block = (t, c, ktile of 128 kpoints), 256 thr (4 waves).
// GEMM C1[y(m)=128, kpoint(n)=128] over K'=256 (x interleaved r/i), chunks of 32.
// A = srcB rows (LDS ping-pong, padded 40 halves/row), B = ExC rows (global).
// Epilogue: kdat[k] = sum_y Ey[k,y]*C1[y,k]; g = kdat * dcomp / 16384.
// (v0 verbatim)
// ---------------------------------------------------------------------------
__global__ __launch_bounds__(256) void fwd_gemm(const uint* __restrict__ ExC,
                                                const uint* __restrict__ EyC,
                                                const uint* __restrict__ srcB,
                                                const float* __restrict__ dcomp,
                                                float2* __restrict__ g) {
    const int t = blockIdx.x, c = blockIdx.y, kt = blockIdx.z;
    const int tid = threadIdx.x, lane = tid & 63, ws = tid >> 6;
    const int quad = lane >> 4, l15 = lane & 15;

    __shared__ __align__(16) _Float16 As[2][128][40];   // 32 K'-halves + 8 pad

    f32x4 accr[8][2], acci[8][2];
#pragma unroll
    for (int mf = 0; mf < 8; ++mf)
#pragma unroll
        for (int nf = 0; nf < 2; ++nf) {
            accr[mf][nf] = (f32x4)0.0f;
            acci[mf][nf] = (f32x4)0.0f;
        }

    const uint* srcRow = srcB + (size_t)((t * NC + c) * NXY) * NXY;   // [y][x] dwords
    const uint* exRow  = ExC + ((size_t)t * NK + kt * 128) * NXY;     // [kp_local][x] dwords

    // stage chunk 0
#pragma unroll
    for (int p = 0; p < 2; ++p) {
        int lin = p * 256 + tid, y = lin >> 2, xi = lin & 3;
        F8 v = *(const F8*)(srcRow + y * NXY + xi * 4);
        *(F8*)&As[0][y][xi * 8] = v;
    }
    __syncthreads();

    for (int ch = 0; ch < 8; ++ch) {
        const int buf = ch & 1;
        F8 Bf[2];
#pragma unroll
        for (int nf = 0; nf < 2; ++nf) {
            int kp_local = ws * 32 + nf * 16 + l15;
            Bf[nf] = *(const F8*)(exRow + kp_local * NXY + ch * 16 + quad * 4);
        }
#pragma unroll
        for (int mf = 0; mf < 8; ++mf) {
            F8 Ap = *(const F8*)&As[buf][mf * 16 + l15][quad * 8];
            F8 Ar, Ai;
#pragma unroll
            for (int d = 0; d < 4; ++d) {
                Ar.u[d] = Ap.u[d] ^ 0x80000000u;   // (sR, -sI)
                Ai.u[d] = rot16(Ap.u[d]);          // (sI,  sR)
            }
#pragma unroll
            for (int nf = 0; nf < 2; ++nf) {
                accr[mf][nf] = MFMA16(Ar.h, Bf[nf].h, accr[mf][nf]);
                acci[mf][nf] = MFMA16(Ai.h, Bf[nf].h, acci[mf][nf]);
            }
        }
        if (ch < 7) {
#pragma unroll
            for (int p = 0; p < 2; ++p) {
                int lin = p * 256 + tid, y = lin >> 2, xi = lin & 3;
                F8 v = *(const F8*)(srcRow + y * NXY + (ch + 1) * 16 + xi * 4);
                *(F8*)&As[buf ^ 1][y][xi * 8] = v;
            }
        }
        __syncthreads();
    }

    // epilogue: y-reduction with Ey, then g
    const uint* eyRow = EyC + ((size_t)t * NK + kt * 128) * NXY;
#pragma unroll
    for (int nf = 0; nf < 2; ++nf) {
        const int kp_local = ws * 32 + nf * 16 + l15;
        const int kpoint = kt * 128 + kp_local;
        float kdr = 0.f, kdi = 0.f;
#pragma unroll
        for (int mf = 0; mf < 8; ++mf) {
            F8 e4 = *(const F8*)(eyRow + kp_local * NXY + mf * 16 + quad * 4);
#pragma unroll
            for (int r = 0; r < 4; ++r) {
                float2 ey = unpack2h(e4.u[r]);
                float cr = accr[mf][nf][r], ci = acci[mf][nf][r];
                kdr += ey.x * cr - ey.y * ci;
                kdi += ey.x * ci + ey.y * cr;
            }
        }
        kdr += __shfl_xor(kdr, 16); kdr += __shfl_xor(kdr, 32);
        kdi += __shfl_xor(kdi, 16); kdi += __shfl_xor(kdi, 32);
        if (lane < 16) {
            float w = dcomp[(size_t)kpoint * NT + t] * (1.0f / 16384.0f);
            g[((size_t)t * NK + kpoint) * NC + c] = make_float2(kdr * w, kdi * w);
        }
    }
}

// ---------------------------------------------------------------------------
// adj_gemm: block = (t, ytile of 8 y, kz of 4 k-segments), 512 thr (8 waves).
// GEMM C3[m=(yloc*8+c)=64, x(n)=128] over K'=1024 per block (512 kpoints),
// chunks of 64 halves (32 kpoints). A = t2 = conj(Ey)*g built in LDS ping-pong;
// B = ExT rows (global). Epilogue: coil-combine with conj(smap) -> atomicAdd.
// (v0 body; only kz offsets + atomic epilogue changed)
// ---------------------------------------------------------------------------
__global__ __launch_bounds__(512) void adj_gemm(const uint* __restrict__ ExT,
                                                const uint* __restrict__ EyC,
                                                const float2* __restrict__ g,
                                                const float* __restrict__ csmap,
                                                float* __restrict__ out) {
    const int t = blockIdx.x, yt = blockIdx.y, kz = blockIdx.z, ybase = yt * 8;
    const int tid = threadIdx.x, lane = tid & 63, ws = tid >> 6;
    const int quad = lane >> 4, l15 = lane & 15;
    const int x = ws * 16 + l15;
    const int kbase = kz * 512;

    __shared__ __align__(16) _Float16 Ts[2][64][72];    // 64 K'-halves + 8 pad

    f32x4 accr[4], acci[4];
#pragma unroll
    for (int mf = 0; mf < 4; ++mf) { accr[mf] = (f32x4)0.0f; acci[mf] = (f32x4)0.0f; }

    const float2* gBase = g + (size_t)t * NK * NC;
    const uint* eyBase = EyC + (size_t)t * NK * NXY;
    const uint* exBase = ExT + (size_t)t * NXY * NK;

    const int bm = tid & 63;                 // build: row m
    const int bk4 = (tid >> 6) * 4;          // build: kpoint offset (0..28)
    const int by = ybase + (bm >> 3), bc = bm & 7;

    // build chunk 0
    {
        F8 w;
#pragma unroll
        for (int j = 0; j < 4; ++j) {
            int kp = kbase + bk4 + j;
            float2 gv = gBase[kp * NC + bc];
            float2 ey = unpack2h(eyBase[(size_t)kp * NXY + by]);
            w.u[j] = pack2h(ey.x * gv.x + ey.y * gv.y, ey.x * gv.y - ey.y * gv.x);
        }
        *(F8*)&Ts[0][bm][bk4 * 2] = w;
    }
    __syncthreads();

    for (int ch = 0; ch < 16; ++ch) {
        const int buf = ch & 1;
#pragma unroll
        for (int ks = 0; ks < 2; ++ks) {
            const int kp = kbase + ch * 32 + ks * 16 + quad * 4;
            F8 Bf = *(const F8*)(exBase + (size_t)x * NK + kp);
#pragma unroll
            for (int mf = 0; mf < 4; ++mf) {
                F8 Ap = *(const F8*)&Ts[buf][mf * 16 + l15][ks * 32 + quad * 8];
                F8 Ai;
#pragma unroll
                for (int d = 0; d < 4; ++d) Ai.u[d] = rot16(Ap.u[d]) ^ 0x80000000u; // (t2I, -t2R)
                accr[mf] = MFMA16(Ap.h, Bf.h, accr[mf]);
                acci[mf] = MFMA16(Ai.h, Bf.h, acci[mf]);
            }
        }
        if (ch < 15) {
            F8 w;
#pragma unroll
            for (int j = 0; j < 4; ++j) {
                int kp = kbase + (ch + 1) * 32 + bk4 + j;
                float2 gv = gBase[kp * NC + bc];
                float2 ey = unpack2h(eyBase[(size_t)kp * NXY + by]);
                w.u[j] = pack2h(ey.x * gv.x + ey.y * gv.y, ey.x * gv.y - ey.y * gv.x);
            }
            *(F8*)&Ts[buf ^ 1][bm][bk4 * 2] = w;
        }
        __syncthreads();
    }

    // epilogue: coil-combine with conj(smap), atomicAdd into zeroed out
#pragma unroll
    for (int mf = 0; mf < 4; ++mf) {
        const int y = ybase + 2 * mf + (quad >> 1);
        float or_ = 0.f, oi_ = 0.f;
#pragma unroll
        for (int r = 0; r < 4; ++r) {
            int c = 4 * (quad & 1) + r;
            float sr = csmap[(size_t)c * 2 * NXY * NXY + x * NXY + y];
            float si = csmap[(size_t)c * 2 * NXY * NXY + NXY * NXY + x * NXY + y];
            float xr = accr[mf][r], xi = acci[mf][r];
            or_ += sr * xr + si * xi;
            oi_ += sr * xi - si * xr;
        }
        or_ += __shfl_xor(or_, 16);
        oi_ += __shfl_xor(oi_, 16);
        if ((lane & 16) == 0) {
            atomicAdd(out + (size_t)(x * NXY + y) * NT + t, or_);
            atomicAdd(out + (size_t)NXY * NXY * NT + (size_t)(x * NXY + y) * NT + t, oi_);
        }
    }
}

// ---------------------------------------------------------------------------
extern "C" void kernel_launch(void* const* d_in, const int* in_sizes, int n_in,
                              void* d_out, int out_size, void* d_ws, size_t ws_size,
                              hipStream_t stream) {
    const float* xin   = (const float*)d_in[0];  // (2,128,128,16)
    const float* ktraj = (const float*)d_in[1];  // (2,2048,16)
    const float* csmap = (const float*)d_in[2];  // (8,2,128,128)
    const float* dcomp = (const float*)d_in[3];  // (2048,16)
    float* out = (float*)d_out;                  // (2,128,128,16)

    // ws layout (dwords of packed complex fp16, then fp32 g): ~60 MB total
    const size_t TBL = (size_t)NT * NK * NXY;        // dwords per phasor table
    uint* ExC  = (uint*)d_ws;                        // [t][k][x]
    uint* ExT  = ExC + TBL;                          // [t][x][k]
    uint* EyC  = ExT + TBL;                          // [t][k][y]
    uint* srcB = EyC + TBL;                          // [t][c][y][x]
    float2* g  = (float2*)(srcB + (size_t)NT * NC * NXY * NXY);  // [t][k][c]

    hipMemsetAsync(d_out, 0, (size_t)out_size, stream);  // adj accumulates atomically
    prep_phasA<<<dim3(NT, NK / 2), 256, 0, stream>>>(ktraj, ExC, EyC);
    prep_phasB<<<dim3(NT, NXY, NK / 256), 256, 0, stream>>>(ktraj, ExT);
    prep_src<<<dim3((NT * NC * NXY * NXY) / 256), 256, 0, stream>>>(xin, csmap, srcB);
    fwd_gemm<<<dim3(NT, NC, NK / 128), 256, 0, stream>>>(ExC, EyC, srcB, dcomp, g);
    adj_gemm<<<dim3(NT, NXY / 8, 4), 512, 0, stream>>>(ExT, EyC, g, csmap, out);
}

// Round 4
// 254.705 us; speedup vs baseline: 1.6635x; 1.3339x over previous
//
#include <hip/hip_runtime.h>

// Frame-wise E^H D E exact NDFT via separable phasors as two complex GEMMs on
// fp16 matrix cores (fp32 accumulate).
// v5 = best-of-each-round:
//  - adj_gemm: v0 body (kz=1, 512thr, 48 VGPR, plain stores) + address-only fixes:
//      B loads from ExB[t][kp>>2][x][kp&3]  -> 256B-contiguous runs (4x fewer trans)
//      epilogue csmap from csmapT[c][ri][y][x] -> x-coalesced
//  - fwd_gemm: v3 body (tiled ExC/EyC, fragment-ordered srcB, reg prefetch),
//      __launch_bounds__(256,2) so ~130 live VGPRs cannot spill.
//  - preps: direct sincos, every kernel read- and write-coalesced.

#define NT 16
#define NK 2048
#define NXY 128
#define NC 8

typedef _Float16 f16x8 __attribute__((ext_vector_type(8)));
typedef float f32x4 __attribute__((ext_vector_type(4)));

union F8 { f16x8 h; uint u[4]; };

#define MFMA16(a, b, c) __builtin_amdgcn_mfma_f32_16x16x32_f16((a), (b), (c), 0, 0, 0)

__device__ __forceinline__ uint pack2h(float a, float b) {
    union { _Float16 h[2]; uint u; } p;
    p.h[0] = (_Float16)a; p.h[1] = (_Float16)b;
    return p.u;
}
__device__ __forceinline__ float2 unpack2h(uint v) {
    union { uint u; _Float16 h[2]; } p;
    p.u = v;
    return make_float2((float)p.h[0], (float)p.h[1]);
}
__device__ __forceinline__ uint rot16(uint v) { return (v >> 16) | (v << 16); }

// ---------------------------------------------------------------------------
// Tiled ExC/EyC: [t][kt16][xc8][kp128][xq16]; value exp(-i*k*(x-64)).
// Lanes = x -> coalesced stores; k broadcast per half-block.
// ---------------------------------------------------------------------------
__global__ __launch_bounds__(256) void prep_phasA(const float* __restrict__ ktraj,
                                                  uint* __restrict__ ExC,
                                                  uint* __restrict__ EyC) {
    const int t = blockIdx.x;
    const int k = blockIdx.y * 2 + (threadIdx.x >> 7);
    const int x = threadIdx.x & 127;
    const float kx = ktraj[(size_t)k * NT + t];
    const float ky = ktraj[(size_t)(NK + k) * NT + t];
    const float xm = (float)(x - 64);
    const size_t off = ((size_t)(t * 16 + (k >> 7)) * 8 + (x >> 4)) * 2048 +
                       (size_t)(k & 127) * 16 + (x & 15);
    float s, c;
    __sincosf(-kx * xm, &s, &c);
    ExC[off] = pack2h(c, s);
    __sincosf(-ky * xm, &s, &c);
    EyC[off] = pack2h(c, s);
}

// ---------------------------------------------------------------------------
// ExB[t][kg512][x128][kq4]: adj B-fragment layout; idx linear = output linear.
// ---------------------------------------------------------------------------
__global__ __launch_bounds__(256) void prep_phasExB(const float* __restrict__ ktraj,
                                                    uint* __restrict__ ExB) {
    const int idx = blockIdx.x * 256 + threadIdx.x;   // < 16*512*128*4 = 4.19M
    const int kq = idx & 3, x = (idx >> 2) & 127, kg = (idx >> 9) & 511, t = idx >> 18;
    const int kp = kg * 4 + kq;
    const float kx = ktraj[(size_t)kp * NT + t];
    float s, c;
    __sincosf(-kx * (float)(x - 64), &s, &c);
    ExB[idx] = pack2h(c, s);
}

// ---------------------------------------------------------------------------
// csmapT[c][ri][y][x] = csmap[c][ri][x][y]  (x-coalesced epilogue loads)
// ---------------------------------------------------------------------------
__global__ __launch_bounds__(256) void prep_csmapT(const float* __restrict__ csmap,
                                                   float* __restrict__ csmapT) {
    const int idx = blockIdx.x * 256 + threadIdx.x;   // < 8*2*128*128 = 262144
    const int x = idx & 127, y = (idx >> 7) & 127, cri = idx >> 14;
    csmapT[idx] = csmap[((size_t)cri * NXY + x) * NXY + y];
}

// ---------------------------------------------------------------------------
// srcB in MFMA-fragment order: [t][c][ch8][mf8][r16][xl16] dwords,
// element = smap[c,x,y]*img[x,y,t], x = ch*16+xl, y = mf*16+r.
// Lane mapping t-fastest: xin reads are 256B-contiguous per wave.
// ---------------------------------------------------------------------------
__global__ __launch_bounds__(256) void prep_src(const float* __restrict__ xin,
                                                const float* __restrict__ csmap,
                                                uint* __restrict__ srcB) {
    const int idx = blockIdx.x * 256 + threadIdx.x;   // < 2^21
    const int t = idx & 15, r = (idx >> 4) & 15, xl = (idx >> 8) & 15,
              mf = (idx >> 12) & 7, ch = (idx >> 15) & 7, c = idx >> 18;
    const int x = ch * 16 + xl, y = mf * 16 + r;
    const float ir = xin[(size_t)(x * NXY + y) * NT + t];
    const float ii = xin[(size_t)NXY * NXY * NT + (size_t)(x * NXY + y) * NT + t];
    const float sr = csmap[(size_t)c * 2 * NXY * NXY + x * NXY + y];
    const float si = csmap[(size_t)c * 2 * NXY * NXY + NXY * NXY + x * NXY + y];
    srcB[((size_t)(t * NC + c) << 14) + ch * 2048 + mf * 256 + r * 16 + xl] =
        pack2h(sr * ir - si * ii, sr * ii + si * ir);
}

// ---------------------------------------------------------------------------
// fwd_gemm: block = (t, c, kt of 64 kpoints), 256 thr (4 waves: 2 mh x 2 nq).
// C1[y=128, kp=64] over K'=256, 8 chunks. Fragment-ordered LDS (contiguous
// stage/read), B + A prefetched one chunk ahead in registers. (v3 body)
// ---------------------------------------------------------------------------
__global__ __launch_bounds__(256, 2) void fwd_gemm(const uint* __restrict__ ExC,
                                                   const uint* __restrict__ EyC,
                                                   const uint* __restrict__ srcB,
                                                   const float* __restrict__ dcomp,
                                                   float2* __restrict__ g) {
    const int t = blockIdx.x, c = blockIdx.y, kt = blockIdx.z;
    const int tid = threadIdx.x, lane = tid & 63, ws = tid >> 6;
    const int quad = lane >> 4, l15 = lane & 15;
    const int mh = ws >> 1, nq = ws & 1;

    __shared__ __align__(16) _Float16 As[2][4096];

    f32x4 accr[4][2], acci[4][2];
#pragma unroll
    for (int mf = 0; mf < 4; ++mf)
#pragma unroll
        for (int nf = 0; nf < 2; ++nf) { accr[mf][nf] = (f32x4)0.0f; acci[mf][nf] = (f32x4)0.0f; }

    const uint* srcT = srcB + ((size_t)(t * NC + c) << 14);
    const uint* exB = ExC + (size_t)(t * 16 + (kt >> 1)) * 16384;
    const int kin0 = (kt & 1) * 64 + nq * 32;            // kp base within 128-tile

    // prologue: stage + B loads for chunk 0
    F8 vA0 = *(const F8*)(srcT + tid * 8);
    F8 vA1 = *(const F8*)(srcT + tid * 8 + 4);
    F8 Bc0 = *(const F8*)(exB + (kin0 + l15) * 16 + quad * 4);
    F8 Bc1 = *(const F8*)(exB + (kin0 + 16 + l15) * 16 + quad * 4);

#pragma unroll 2
    for (int ch = 0; ch < 8; ++ch) {
        const int buf = ch & 1;
        *(F8*)&As[buf][tid * 16] = vA0;
        *(F8*)&As[buf][tid * 16 + 8] = vA1;
        __syncthreads();
        const int chn = ch < 7 ? ch + 1 : 7;
        vA0 = *(const F8*)(srcT + chn * 2048 + tid * 8);
        vA1 = *(const F8*)(srcT + chn * 2048 + tid * 8 + 4);
        F8 Bn0 = *(const F8*)(exB + chn * 2048 + (kin0 + l15) * 16 + quad * 4);
        F8 Bn1 = *(const F8*)(exB + chn * 2048 + (kin0 + 16 + l15) * 16 + quad * 4);
        __builtin_amdgcn_sched_barrier(0);
#pragma unroll
        for (int mf = 0; mf < 4; ++mf) {
            F8 Ap = *(const F8*)&As[buf][(mh * 4 + mf) * 512 + l15 * 32 + quad * 8];
            F8 Ar, Ai;
#pragma unroll
            for (int d = 0; d < 4; ++d) {
                Ar.u[d] = Ap.u[d] ^ 0x80000000u;   // (sR, -sI)
                Ai.u[d] = rot16(Ap.u[d]);          // (sI,  sR)
            }
            accr[mf][0] = MFMA16(Ar.h, Bc0.h, accr[mf][0]);
            acci[mf][0] = MFMA16(Ai.h, Bc0.h, acci[mf][0]);
            accr[mf][1] = MFMA16(Ar.h, Bc1.h, accr[mf][1]);
            acci[mf][1] = MFMA16(Ai.h, Bc1.h, acci[mf][1]);
        }
        Bc0 = Bn0; Bc1 = Bn1;
    }

    // epilogue: partial y-reduction with Ey per mh-half, LDS combine
    __syncthreads();
    float* red = (float*)(&As[0][0]);
    const uint* eyB = EyC + (size_t)(t * 16 + (kt >> 1)) * 16384;
#pragma unroll
    for (int nf = 0; nf < 2; ++nf) {
        const int kin = kin0 + nf * 16 + l15;
        float kdr = 0.f, kdi = 0.f;
#pragma unroll
        for (int mf = 0; mf < 4; ++mf) {
            const int yc = mh * 4 + mf;
            F8 e4 = *(const F8*)(eyB + yc * 2048 + kin * 16 + quad * 4);
#pragma unroll
            for (int rr = 0; rr < 4; ++rr) {
                float2 ey = unpack2h(e4.u[rr]);
                float cr = accr[mf][nf][rr], ci = acci[mf][nf][rr];
                kdr += ey.x * cr - ey.y * ci;
                kdi += ey.x * ci + ey.y * cr;
            }
        }
        kdr += __shfl_xor(kdr, 16); kdr += __shfl_xor(kdr, 32);
        kdi += __shfl_xor(kdi, 16); kdi += __shfl_xor(kdi, 32);
        if (lane < 16) {
            const int kl = nq * 32 + nf * 16 + l15;       // 0..63
            red[(mh * 64 + kl) * 2] = kdr;
            red[(mh * 64 + kl) * 2 + 1] = kdi;
        }
    }
    __syncthreads();
    if (tid < 64) {
        const int kpoint = kt * 64 + tid;
        const float kdr = red[tid * 2] + red[(64 + tid) * 2];
        const float kdi = red[tid * 2 + 1] + red[(64 + tid) * 2 + 1];
        const float w = dcomp[(size_t)kpoint * NT + t] * (1.0f / 16384.0f);
        g[((size_t)t * NK + kpoint) * NC + c] = make_float2(kdr * w, kdi * w);
    }
}

// ---------------------------------------------------------------------------
// adj_gemm: block = (t, ytile of 8 y), 512 thr (8 waves).  (v0 body)
// C3[m=(yloc*8+c)=64, x=128] over K'=4096 (2048 kpoints), 64 chunks of 32 kp.
// A = t2 = conj(Ey)*g built in LDS ping-pong (g/ey loads broadcast-coalesced);
// B from ExB (256B-contiguous fragment runs).  Epilogue: conj(smap) via
// csmapT (x-coalesced), plain stores.
// ---------------------------------------------------------------------------
__global__ __launch_bounds__(512) void adj_gemm(const uint* __restrict__ ExB,
                                                const uint* __restrict__ EyC,
                                                const float2* __restrict__ g,
                                                const float* __restrict__ csmapT,
                                                float* __restrict__ out) {
    const int t = blockIdx.x, yt = blockIdx.y, ybase = yt * 8;
    const int tid = threadIdx.x, lane = tid & 63, ws = tid >> 6;
    const int quad = lane >> 4, l15 = lane & 15;
    const int x = ws * 16 + l15;

    __shared__ __align__(16) _Float16 Ts[2][64][72];    // 64 K'-halves + 8 pad

    f32x4 accr[4], acci[4];
#pragma unroll
    for (int mf = 0; mf < 4; ++mf) { accr[mf] = (f32x4)0.0f; acci[mf] = (f32x4)0.0f; }

    const float2* gBase = g + (size_t)t * NK * NC;
    const uint* eyT = EyC + (size_t)t * 262144;          // tiled [kt][yc][kp][yq]
    const uint* exbT = ExB + (size_t)t * 262144;         // [kg][x][kq]

    const int bm = tid & 63;                 // build: row m
    const int bk4 = (tid >> 6) * 4;          // build: kpoint offset (0..28)
    const int by = ybase + (bm >> 3), bc = bm & 7;
    const int ybank = (by >> 4) * 2048 + (by & 15);

    // build chunk 0
    {
        F8 w;
#pragma unroll
        for (int j = 0; j < 4; ++j) {
            int kp = bk4 + j;
            float2 gv = gBase[kp * NC + bc];
            float2 ey = unpack2h(eyT[(size_t)(kp >> 7) * 16384 + (size_t)(kp & 127) * 16 + ybank]);
            w.u[j] = pack2h(ey.x * gv.x + ey.y * gv.y, ey.x * gv.y - ey.y * gv.x);
        }
        *(F8*)&Ts[0][bm][bk4 * 2] = w;
    }
    __syncthreads();

    for (int ch = 0; ch < 64; ++ch) {
        const int buf = ch & 1;
#pragma unroll
        for (int ks = 0; ks < 2; ++ks) {
            const int kg = ch * 8 + ks * 4 + quad;       // kp group of 4
            F8 Bf = *(const F8*)(exbT + ((size_t)kg * 128 + x) * 4);
#pragma unroll
            for (int mf = 0; mf < 4; ++mf) {
                F8 Ap = *(const F8*)&Ts[buf][mf * 16 + l15][ks * 32 + quad * 8];
                F8 Ai;
#pragma unroll
                for (int d = 0; d < 4; ++d) Ai.u[d] = rot16(Ap.u[d]) ^ 0x80000000u; // (t2I, -t2R)
                accr[mf] = MFMA16(Ap.h, Bf.h, accr[mf]);
                acci[mf] = MFMA16(Ai.h, Bf.h, acci[mf]);
            }
        }
        if (ch < 63) {
            F8 w;
#pragma unroll
            for (int j = 0; j < 4; ++j) {
                int kp = (ch + 1) * 32 + bk4 + j;
                float2 gv = gBase[kp * NC + bc];
                float2 ey = unpack2h(eyT[(size_t)(kp >> 7) * 16384 + (size_t)(kp & 127) * 16 + ybank]);
                w.u[j] = pack2h(ey.x * gv.x + ey.y * gv.y, ey.x * gv.y - ey.y * gv.x);
            }
            *(F8*)&Ts[buf ^ 1][bm][bk4 * 2] = w;
        }
        __syncthreads();
    }

    // epilogue: coil-combine with conj(smap) via csmapT, plain stores
#pragma unroll
    for (int mf = 0; mf < 4; ++mf) {
        const int y = ybase + 2 * mf + (quad >> 1);
        float or_ = 0.f, oi_ = 0.f;
#pragma unroll
        for (int r = 0; r < 4; ++r) {
            int c = 4 * (quad & 1) + r;
            float sr = csmapT[((size_t)(c * 2) * NXY + y) * NXY + x];
            float si = csmapT[((size_t)(c * 2 + 1) * NXY + y) * NXY + x];
            float xr = accr[mf][r], xi = acci[mf][r];
            or_ += sr * xr + si * xi;
            oi_ += sr * xi - si * xr;
        }
        or_ += __shfl_xor(or_, 16);
        oi_ += __shfl_xor(oi_, 16);
        if ((lane & 16) == 0) {
            out[(size_t)(x * NXY + y) * NT + t] = or_;
            out[(size_t)NXY * NXY * NT + (size_t)(x * NXY + y) * NT + t] = oi_;
        }
    }
}

// ---------------------------------------------------------------------------
extern "C" void kernel_launch(void* const* d_in, const int* in_sizes, int n_in,
                              void* d_out, int out_size, void* d_ws, size_t ws_size,
                              hipStream_t stream) {
    const float* xin   = (const float*)d_in[0];  // (2,128,128,16)
    const float* ktraj = (const float*)d_in[1];  // (2,2048,16)
    const float* csmap = (const float*)d_in[2];  // (8,2,128,128)
    const float* dcomp = (const float*)d_in[3];  // (2048,16)
    float* out = (float*)d_out;                  // (2,128,128,16)

    // ws layout: 3 phasor tables (16 MiB each) + srcB 8 MiB + g 2 MiB + csmapT 1 MiB
    const size_t TBL = (size_t)NT * NK * NXY;            // 4.19M dwords per table
    uint* ExC  = (uint*)d_ws;                            // [t][kt][xc][kp][xq]
    uint* ExB  = ExC + TBL;                              // [t][kg][x][kq]
    uint* EyC  = ExB + TBL;                              // [t][kt][yc][kp][yq]
    uint* srcB = EyC + TBL;                              // fragment-ordered
    float2* g  = (float2*)(srcB + (size_t)NT * NC * NXY * NXY);  // [t][k][c]
    float* csmapT = (float*)(g + (size_t)NT * NK * NC);  // [c][ri][y][x]

    prep_phasA<<<dim3(NT, NK / 2), 256, 0, stream>>>(ktraj, ExC, EyC);
    prep_phasExB<<<dim3(16384), 256, 0, stream>>>(ktraj, ExB);
    prep_csmapT<<<dim3(1024), 256, 0, stream>>>(csmap, csmapT);
    prep_src<<<dim3(8192), 256, 0, stream>>>(xin, csmap, srcB);
    fwd_gemm<<<dim3(NT, NC, 32), 256, 0, stream>>>(ExC, EyC, srcB, dcomp, g);
    adj_gemm<<<dim3(NT, NXY / 8), 512, 0, stream>>>(ExB, EyC, g, csmapT, out);
}

// Round 5
// 244.892 us; speedup vs baseline: 1.7302x; 1.0401x over previous
//
#include <hip/hip_runtime.h>

// Frame-wise E^H D E exact NDFT via separable phasors as two complex GEMMs on
// fp16 matrix cores (fp32 accumulate).
// v6 = composition of measured-best pieces:
//  - adj_gemm: v0 body VERBATIM (94.7us measured): ExT[t][x][k] B-loads
//    (8KB-strided lane pattern -> good L2 channel spread), linear EyL build,
//    original csmap epilogue, plain stores. v5's "coalesced" ExB/tiled-Ey adj
//    regressed to 119.9us (channel serialization) -> reverted.
//  - fwd_gemm: v5 body (fragment-ordered srcB, reg prefetch, (256,2)) with the
//    epilogue reading linear EyL (so only one Ey layout is materialized).
//  - preps: direct sincos, all store-coalesced. ws = 3 tables + srcB + g = 58MB.

#define NT 16
#define NK 2048
#define NXY 128
#define NC 8

typedef _Float16 f16x8 __attribute__((ext_vector_type(8)));
typedef float f32x4 __attribute__((ext_vector_type(4)));

union F8 { f16x8 h; uint u[4]; };

#define MFMA16(a, b, c) __builtin_amdgcn_mfma_f32_16x16x32_f16((a), (b), (c), 0, 0, 0)

__device__ __forceinline__ uint pack2h(float a, float b) {
    union { _Float16 h[2]; uint u; } p;
    p.h[0] = (_Float16)a; p.h[1] = (_Float16)b;
    return p.u;
}
__device__ __forceinline__ float2 unpack2h(uint v) {
    union { uint u; _Float16 h[2]; } p;
    p.u = v;
    return make_float2((float)p.h[0], (float)p.h[1]);
}
__device__ __forceinline__ uint rot16(uint v) { return (v >> 16) | (v << 16); }

// ---------------------------------------------------------------------------
// prep_phasA: tiled ExC [t][kt16][xc8][kp128][xq16] (fwd main-loop B) and
// linear EyL [t][k][y] (adj build + fwd epilogue). exp(-i*k*(coord-64)).
// Lanes = coord -> coalesced stores; k broadcast per half-block.
// ---------------------------------------------------------------------------
__global__ __launch_bounds__(256) void prep_phasA(const float* __restrict__ ktraj,
                                                  uint* __restrict__ ExC,
                                                  uint* __restrict__ EyL) {
    const int t = blockIdx.x;
    const int k = blockIdx.y * 2 + (threadIdx.x >> 7);
    const int x = threadIdx.x & 127;
    const float kx = ktraj[(size_t)k * NT + t];
    const float ky = ktraj[(size_t)(NK + k) * NT + t];
    const float xm = (float)(x - 64);
    float s, c;
    __sincosf(-kx * xm, &s, &c);
    ExC[((size_t)(t * 16 + (k >> 7)) * 8 + (x >> 4)) * 2048 +
        (size_t)(k & 127) * 16 + (x & 15)] = pack2h(c, s);
    __sincosf(-ky * xm, &s, &c);
    EyL[((size_t)t * NK + k) * NXY + x] = pack2h(c, s);
}

// ---------------------------------------------------------------------------
// ExT[t][x][k]; lanes = k -> contiguous 1KB store runs. (adj B-loads)
// ---------------------------------------------------------------------------
__global__ __launch_bounds__(256) void prep_phasB(const float* __restrict__ ktraj,
                                                  uint* __restrict__ ExT) {
    const int t = blockIdx.x, x = blockIdx.y;
    const int k = blockIdx.z * 256 + threadIdx.x;
    const float kx = ktraj[(size_t)k * NT + t];
    float s, c;
    __sincosf(-kx * (float)(x - 64), &s, &c);
    ExT[((size_t)t * NXY + x) * NK + k] = pack2h(c, s);
}

// ---------------------------------------------------------------------------
// srcB in MFMA-fragment order: [t][c][ch8][mf8][r16][xl16] dwords,
// element = smap[c,x,y]*img[x,y,t], x = ch*16+xl, y = mf*16+r.
// Lane mapping t-fastest: xin reads are 256B-contiguous per wave.
// ---------------------------------------------------------------------------
__global__ __launch_bounds__(256) void prep_src(const float* __restrict__ xin,
                                                const float* __restrict__ csmap,
                                                uint* __restrict__ srcB) {
    const int idx = blockIdx.x * 256 + threadIdx.x;   // < 2^21
    const int t = idx & 15, r = (idx >> 4) & 15, xl = (idx >> 8) & 15,
              mf = (idx >> 12) & 7, ch = (idx >> 15) & 7, c = idx >> 18;
    const int x = ch * 16 + xl, y = mf * 16 + r;
    const float ir = xin[(size_t)(x * NXY + y) * NT + t];
    const float ii = xin[(size_t)NXY * NXY * NT + (size_t)(x * NXY + y) * NT + t];
    const float sr = csmap[(size_t)c * 2 * NXY * NXY + x * NXY + y];
    const float si = csmap[(size_t)c * 2 * NXY * NXY + NXY * NXY + x * NXY + y];
    srcB[((size_t)(t * NC + c) << 14) + ch * 2048 + mf * 256 + r * 16 + xl] =
        pack2h(sr * ir - si * ii, sr * ii + si * ir);
}

// ---------------------------------------------------------------------------
// fwd_gemm: block = (t, c, kt of 64 kpoints), 256 thr (4 waves: 2 mh x 2 nq).
// C1[y=128, kp=64] over K'=256, 8 chunks. Fragment-ordered LDS (contiguous
// stage/read), B + A prefetched one chunk ahead in registers. (v5 body;
// epilogue reads linear EyL.)
// ---------------------------------------------------------------------------
__global__ __launch_bounds__(256, 2) void fwd_gemm(const uint* __restrict__ ExC,
                                                   const uint* __restrict__ EyL,
                                                   const uint* __restrict__ srcB,
                                                   const float* __restrict__ dcomp,
                                                   float2* __restrict__ g) {
    const int t = blockIdx.x, c = blockIdx.y, kt = blockIdx.z;
    const int tid = threadIdx.x, lane = tid & 63, ws = tid >> 6;
    const int quad = lane >> 4, l15 = lane & 15;
    const int mh = ws >> 1, nq = ws & 1;

    __shared__ __align__(16) _Float16 As[2][4096];

    f32x4 accr[4][2], acci[4][2];
#pragma unroll
    for (int mf = 0; mf < 4; ++mf)
#pragma unroll
        for (int nf = 0; nf < 2; ++nf) { accr[mf][nf] = (f32x4)0.0f; acci[mf][nf] = (f32x4)0.0f; }

    const uint* srcT = srcB + ((size_t)(t * NC + c) << 14);
    const uint* exB = ExC + (size_t)(t * 16 + (kt >> 1)) * 16384;
    const int kin0 = (kt & 1) * 64 + nq * 32;            // kp base within 128-tile

    // prologue: stage + B loads for chunk 0
    F8 vA0 = *(const F8*)(srcT + tid * 8);
    F8 vA1 = *(const F8*)(srcT + tid * 8 + 4);
    F8 Bc0 = *(const F8*)(exB + (kin0 + l15) * 16 + quad * 4);
    F8 Bc1 = *(const F8*)(exB + (kin0 + 16 + l15) * 16 + quad * 4);

#pragma unroll 2
    for (int ch = 0; ch < 8; ++ch) {
        const int buf = ch & 1;
        *(F8*)&As[buf][tid * 16] = vA0;
        *(F8*)&As[buf][tid * 16 + 8] = vA1;
        __syncthreads();
        const int chn = ch < 7 ? ch + 1 : 7;
        vA0 = *(const F8*)(srcT + chn * 2048 + tid * 8);
        vA1 = *(const F8*)(srcT + chn * 2048 + tid * 8 + 4);
        F8 Bn0 = *(const F8*)(exB + chn * 2048 + (kin0 + l15) * 16 + quad * 4);
        F8 Bn1 = *(const F8*)(exB + chn * 2048 + (kin0 + 16 + l15) * 16 + quad * 4);
        __builtin_amdgcn_sched_barrier(0);
#pragma unroll
        for (int mf = 0; mf < 4; ++mf) {
            F8 Ap = *(const F8*)&As[buf][(mh * 4 + mf) * 512 + l15 * 32 + quad * 8];
            F8 Ar, Ai;
#pragma unroll
            for (int d = 0; d < 4; ++d) {
                Ar.u[d] = Ap.u[d] ^ 0x80000000u;   // (sR, -sI)
                Ai.u[d] = rot16(Ap.u[d]);          // (sI,  sR)
            }
            accr[mf][0] = MFMA16(Ar.h, Bc0.h, accr[mf][0]);
            acci[mf][0] = MFMA16(Ai.h, Bc0.h, acci[mf][0]);
            accr[mf][1] = MFMA16(Ar.h, Bc1.h, accr[mf][1]);
            acci[mf][1] = MFMA16(Ai.h, Bc1.h, acci[mf][1]);
        }
        Bc0 = Bn0; Bc1 = Bn1;
    }

    // epilogue: partial y-reduction with Ey (linear layout) per mh-half, LDS combine
    __syncthreads();
    float* red = (float*)(&As[0][0]);
#pragma unroll
    for (int nf = 0; nf < 2; ++nf) {
        const int kin = kin0 + nf * 16 + l15;                   // kp within 128-tile
        const int kpoint = (kt >> 1) * 128 + kin;
        const uint* eyRow = EyL + ((size_t)t * NK + kpoint) * NXY;
        float kdr = 0.f, kdi = 0.f;
#pragma unroll
        for (int mf = 0; mf < 4; ++mf) {
            const int yc = mh * 4 + mf;
            F8 e4 = *(const F8*)(eyRow + yc * 16 + quad * 4);
#pragma unroll
            for (int rr = 0; rr < 4; ++rr) {
                float2 ey = unpack2h(e4.u[rr]);
                float cr = accr[mf][nf][rr], ci = acci[mf][nf][rr];
                kdr += ey.x * cr - ey.y * ci;
                kdi += ey.x * ci + ey.y * cr;
            }
        }
        kdr += __shfl_xor(kdr, 16); kdr += __shfl_xor(kdr, 32);
        kdi += __shfl_xor(kdi, 16); kdi += __shfl_xor(kdi, 32);
        if (lane < 16) {
            const int kl = nq * 32 + nf * 16 + l15;       // 0..63
            red[(mh * 64 + kl) * 2] = kdr;
            red[(mh * 64 + kl) * 2 + 1] = kdi;
        }
    }
    __syncthreads();
    if (tid < 64) {
        const int kpoint = kt * 64 + tid;
        const float kdr = red[tid * 2] + red[(64 + tid) * 2];
        const float kdi = red[tid * 2 + 1] + red[(64 + tid) * 2 + 1];
        const float w = dcomp[(size_t)kpoint * NT + t] * (1.0f / 16384.0f);
        g[((size_t)t * NK + kpoint) * NC + c] = make_float2(kdr * w, kdi * w);
    }
}

// ---------------------------------------------------------------------------
// adj_gemm: block = (t, ytile of 8 y), 512 thr (8 waves).  (v0 body VERBATIM)
// GEMM C3[m=(yloc*8+c)=64, x(n)=128] over K'=4096 (kpoints interleaved r/i),
// chunks of 64 halves (32 kpoints). A = t2 = conj(Ey)*g built in LDS ping-pong;
// B = ExT rows (global). Epilogue: coil-combine with conj(smap) -> out.
// ---------------------------------------------------------------------------
__global__ __launch_bounds__(512) void adj_gemm(const uint* __restrict__ ExT,
                                                const uint* __restrict__ EyL,
                                                const float2* __restrict__ g,
                                                const float* __restrict__ csmap,
                                                float* __restrict__ out) {
    const int t = blockIdx.x, yt = blockIdx.y, ybase = yt * 8;
    const int tid = threadIdx.x, lane = tid & 63, ws = tid >> 6;
    const int quad = lane >> 4, l15 = lane & 15;
    const int x = ws * 16 + l15;

    __shared__ __align__(16) _Float16 Ts[2][64][72];    // 64 K'-halves + 8 pad

    f32x4 accr[4], acci[4];
#pragma unroll
    for (int mf = 0; mf < 4; ++mf) { accr[mf] = (f32x4)0.0f; acci[mf] = (f32x4)0.0f; }

    const float2* gBase = g + (size_t)t * NK * NC;
    const uint* eyBase = EyL + (size_t)t * NK * NXY;
    const uint* exBase = ExT + (size_t)t * NXY * NK;

    const int bm = tid & 63;                 // build: row m
    const int bk4 = (tid >> 6) * 4;          // build: kpoint offset (0..28)
    const int by = ybase + (bm >> 3), bc = bm & 7;

    // build chunk 0
    {
        F8 w;
#pragma unroll
        for (int j = 0; j < 4; ++j) {
            int kp = bk4 + j;
            float2 gv = gBase[kp * NC + bc];
            float2 ey = unpack2h(eyBase[(size_t)kp * NXY + by]);
            w.u[j] = pack2h(ey.x * gv.x + ey.y * gv.y, ey.x * gv.y - ey.y * gv.x);
        }
        *(F8*)&Ts[0][bm][bk4 * 2] = w;
    }
    __syncthreads();

    for (int ch = 0; ch < 64; ++ch) {
        const int buf = ch & 1;
#pragma unroll
        for (int ks = 0; ks < 2; ++ks) {
            const int kp = ch * 32 + ks * 16 + quad * 4;
            F8 Bf = *(const F8*)(exBase + (size_t)x * NK + kp);
#pragma unroll
            for (int mf = 0; mf < 4; ++mf) {
                F8 Ap = *(const F8*)&Ts[buf][mf * 16 + l15][ks * 32 + quad * 8];
                F8 Ai;
#pragma unroll
                for (int d = 0; d < 4; ++d) Ai.u[d] = rot16(Ap.u[d]) ^ 0x80000000u; // (t2I, -t2R)
                accr[mf] = MFMA16(Ap.h, Bf.h, accr[mf]);
                acci[mf] = MFMA16(Ai.h, Bf.h, acci[mf]);
            }
        }
        if (ch < 63) {
            F8 w;
#pragma unroll
            for (int j = 0; j < 4; ++j) {
                int kp = (ch + 1) * 32 + bk4 + j;
                float2 gv = gBase[kp * NC + bc];
                float2 ey = unpack2h(eyBase[(size_t)kp * NXY + by]);
                w.u[j] = pack2h(ey.x * gv.x + ey.y * gv.y, ey.x * gv.y - ey.y * gv.x);
            }
            *(F8*)&Ts[buf ^ 1][bm][bk4 * 2] = w;
        }
        __syncthreads();
    }

    // epilogue: coil-combine with conj(smap), write out[2][x][y][t]
#pragma unroll
    for (int mf = 0; mf < 4; ++mf) {
        const int y = ybase + 2 * mf + (quad >> 1);
        float or_ = 0.f, oi_ = 0.f;
#pragma unroll
        for (int r = 0; r < 4; ++r) {
            int c = 4 * (quad & 1) + r;
            float sr = csmap[(size_t)c * 2 * NXY * NXY + x * NXY + y];
            float si = csmap[(size_t)c * 2 * NXY * NXY + NXY * NXY + x * NXY + y];
            float xr = accr[mf][r], xi = acci[mf][r];
            or_ += sr * xr + si * xi;
            oi_ += sr * xi - si * xr;
        }
        or_ += __shfl_xor(or_, 16);
        oi_ += __shfl_xor(oi_, 16);
        if ((lane & 16) == 0) {
            out[(size_t)(x * NXY + y) * NT + t] = or_;
            out[(size_t)NXY * NXY * NT + (size_t)(x * NXY + y) * NT + t] = oi_;
        }
    }
}

// ---------------------------------------------------------------------------
extern "C" void kernel_launch(void* const* d_in, const int* in_sizes, int n_in,
                              void* d_out, int out_size, void* d_ws, size_t ws_size,
                              hipStream_t stream) {
    const float* xin   = (const float*)d_in[0];  // (2,128,128,16)
    const float* ktraj = (const float*)d_in[1];  // (2,2048,16)
    const float* csmap = (const float*)d_in[2];  // (8,2,128,128)
    const float* dcomp = (const float*)d_in[3];  // (2048,16)
    float* out = (float*)d_out;                  // (2,128,128,16)

    // ws layout: ExC + ExT + EyL (16MB each) + srcB 8MB + g 2MB = 58MB
    const size_t TBL = (size_t)NT * NK * NXY;            // 4.19M dwords per table
    uint* ExC  = (uint*)d_ws;                            // [t][kt][xc][kp][xq]
    uint* ExT  = ExC + TBL;                              // [t][x][k]
    uint* EyL  = ExT + TBL;                              // [t][k][y]
    uint* srcB = EyL + TBL;                              // fragment-ordered
    float2* g  = (float2*)(srcB + (size_t)NT * NC * NXY * NXY);  // [t][k][c]

    prep_phasA<<<dim3(NT, NK / 2), 256, 0, stream>>>(ktraj, ExC, EyL);
    prep_phasB<<<dim3(NT, NXY, NK / 256), 256, 0, stream>>>(ktraj, ExT);
    prep_src<<<dim3(8192), 256, 0, stream>>>(xin, csmap, srcB);
    fwd_gemm<<<dim3(NT, NC, 32), 256, 0, stream>>>(ExC, EyL, srcB, dcomp, g);
    adj_gemm<<<dim3(NT, NXY / 8), 512, 0, stream>>>(ExT, EyL, g, csmap, out);
}